// Round 3
// baseline (527.544 us; speedup 1.0000x reference)
//
#include <hip/hip_runtime.h>

// Inputs (f32): lower[n], upper[n], alphas[n]   (n = 8192)
// Output (f32), flat in return order:
//   [conc_low (n)] [conc_up (n)] [A_low ((n+1)^2)] [A_up ((n+1)^2)]
// A_low/A_up are diagonal + last row; everything else must be zeroed
// (harness poisons d_out before every call).

__global__ void fill_zero_kernel(float* __restrict__ out, size_t total) {
    size_t idx = blockIdx.x * (size_t)blockDim.x + threadIdx.x;
    size_t stride = (size_t)gridDim.x * blockDim.x;
    size_t nvec = total / 4;                 // 4 f32 per float4 (16 B)
    float4* __restrict__ o4 = (float4*)out;
    const float4 z = make_float4(0.f, 0.f, 0.f, 0.f);
    for (size_t i = idx; i < nvec; i += stride) {
        o4[i] = z;
    }
    size_t tail_start = nvec * 4;
    size_t ntail = total - tail_start;       // total % 4
    if (idx < ntail) {
        out[tail_start + idx] = 0.f;
    }
}

__global__ void relu_relax_kernel(const float* __restrict__ lower,
                                  const float* __restrict__ upper,
                                  const float* __restrict__ alphas,
                                  float* __restrict__ out,
                                  int n) {
    int i = blockIdx.x * blockDim.x + threadIdx.x;
    if (i >= n) return;

    const size_t np1 = (size_t)n + 1;
    const size_t AL = 2 * (size_t)n;              // A_low base
    const size_t AU = AL + np1 * np1;             // A_up base

    float l = lower[i];
    float u = upper[i];
    float a = alphas[i];
    a = fminf(fmaxf(a, 0.f), 1.f);

    bool active   = (u > 0.f) && (l >= 0.f);
    bool unstable = (u > 0.f) && (l < 0.f);

    float denom = u - l;
    float lam = u / ((denom == 0.f) ? 1.f : denom);

    float diag_low = active ? 1.f : (unstable ? a   : 0.f);
    float diag_up  = active ? 1.f : (unstable ? lam : 0.f);
    float bias_up  = unstable ? (-lam * l) : 0.f;
    float conc_low = active ? l : (unstable ? (a * l) : 0.f);
    float conc_up  = (u > 0.f) ? u : 0.f;

    out[i]              = conc_low;
    out[(size_t)n + i]  = conc_up;
    out[AL + (size_t)i * (np1 + 1)] = diag_low;   // A_low[i,i]
    out[AU + (size_t)i * (np1 + 1)] = diag_up;    // A_up[i,i]
    out[AU + (size_t)n * np1 + i]   = bias_up;    // A_up[n, i]

    if (i == 0) {
        out[AL + np1 * np1 - 1] = 1.f;  // A_low[n,n]
        out[AU + np1 * np1 - 1] = 1.f;  // A_up[n,n]
    }
}

extern "C" void kernel_launch(void* const* d_in, const int* in_sizes, int n_in,
                              void* d_out, int out_size, void* d_ws, size_t ws_size,
                              hipStream_t stream) {
    const float* lower  = (const float*)d_in[0];
    const float* upper  = (const float*)d_in[1];
    const float* alphas = (const float*)d_in[2];
    float* out = (float*)d_out;

    const int n = in_sizes[0];               // 8192
    const size_t total = (size_t)out_size;   // 2n + 2*(n+1)^2 f32 elements

    // Zero-fill the whole f32 output (harness poisons d_out before each call).
    fill_zero_kernel<<<8192, 256, 0, stream>>>(out, total);

    // Scatter diagonal / last-row / concrete-bound values (serialized on stream).
    relu_relax_kernel<<<(n + 255) / 256, 256, 0, stream>>>(lower, upper, alphas, out, n);
}

// Round 4
// 517.878 us; speedup vs baseline: 1.0187x; 1.0187x over previous
//
#include <hip/hip_runtime.h>

// Inputs (f32): lower[n], upper[n], alphas[n]   (n = 8192)
// Output (f32), flat in return order:
//   [conc_low (n)] [conc_up (n)] [A_low ((n+1)^2)] [A_up ((n+1)^2)]
// A_low/A_up are diagonal + last row; everything else is zero.
// The harness poisons d_out with 0xAA before every call, so the whole
// 537 MB output must be rewritten each launch. The driver's
// fillBufferAligned sustains 6.25 TB/s on this device (rocprof round 3),
// so we delegate the bulk zero-fill to hipMemsetAsync and only scatter
// the ~50 KB of nonzero values with a tiny kernel.

__global__ void relu_relax_kernel(const float* __restrict__ lower,
                                  const float* __restrict__ upper,
                                  const float* __restrict__ alphas,
                                  float* __restrict__ out,
                                  int n) {
    int i = blockIdx.x * blockDim.x + threadIdx.x;
    if (i >= n) return;

    const size_t np1 = (size_t)n + 1;
    const size_t AL = 2 * (size_t)n;              // A_low base
    const size_t AU = AL + np1 * np1;             // A_up base

    float l = lower[i];
    float u = upper[i];
    float a = alphas[i];
    a = fminf(fmaxf(a, 0.f), 1.f);

    bool active   = (u > 0.f) && (l >= 0.f);
    bool unstable = (u > 0.f) && (l < 0.f);

    float denom = u - l;
    float lam = u / ((denom == 0.f) ? 1.f : denom);

    float diag_low = active ? 1.f : (unstable ? a   : 0.f);
    float diag_up  = active ? 1.f : (unstable ? lam : 0.f);
    float bias_up  = unstable ? (-lam * l) : 0.f;
    float conc_low = active ? l : (unstable ? (a * l) : 0.f);
    float conc_up  = (u > 0.f) ? u : 0.f;

    out[i]              = conc_low;
    out[(size_t)n + i]  = conc_up;
    out[AL + (size_t)i * (np1 + 1)] = diag_low;   // A_low[i,i]
    out[AU + (size_t)i * (np1 + 1)] = diag_up;    // A_up[i,i]
    out[AU + (size_t)n * np1 + i]   = bias_up;    // A_up[n, i]

    if (i == 0) {
        out[AL + np1 * np1 - 1] = 1.f;  // A_low[n,n]
        out[AU + np1 * np1 - 1] = 1.f;  // A_up[n,n]
    }
}

extern "C" void kernel_launch(void* const* d_in, const int* in_sizes, int n_in,
                              void* d_out, int out_size, void* d_ws, size_t ws_size,
                              hipStream_t stream) {
    const float* lower  = (const float*)d_in[0];
    const float* upper  = (const float*)d_in[1];
    const float* alphas = (const float*)d_in[2];
    float* out = (float*)d_out;

    const int n = in_sizes[0];               // 8192
    const size_t total = (size_t)out_size;   // 2n + 2*(n+1)^2 f32 elements

    // Bulk zero-fill via the driver's fill kernel (6.25 TB/s measured).
    hipMemsetAsync(out, 0, total * sizeof(float), stream);

    // Scatter diagonal / last-row / concrete-bound values (serialized on stream).
    relu_relax_kernel<<<(n + 255) / 256, 256, 0, stream>>>(lower, upper, alphas, out, n);
}